// Round 14
// baseline (50.089 us; speedup 1.0000x reference)
//
#include <hip/hip_runtime.h>

#define H 1024
#define W 1024
#define BATCH 16
#define NT 256
#define PXROW 128            // threads across one row-band (8 px each)
#define RPB 8                // image rows per block (2 bands x 4 rows)
#define NRB (H / RPB)        // 128 row-blocks per image
#define NBLK (NRB * BATCH)   // 2048 blocks
#define NXCD 8

typedef float v2 __attribute__((ext_vector_type(2)));
typedef _Float16 h2 __attribute__((ext_vector_type(2)));

__device__ __forceinline__ v2 pmax2(v2 a, v2 b) {
#if __has_builtin(__builtin_elementwise_max)
    return __builtin_elementwise_max(a, b);
#else
    v2 r; r.x = fmaxf(a.x, b.x); r.y = fmaxf(a.y, b.y); return r;
#endif
}

// raw v_sqrt_f32 (~1 ulp) — avoids OCML correctly-rounded fixup sequence
__device__ __forceinline__ float rsq(float x) {
#if __has_builtin(__builtin_amdgcn_sqrtf)
    return __builtin_amdgcn_sqrtf(x);
#else
    return sqrtf(x);
#endif
}

// ---- 12-col window (cols gx-2 .. gx+9) as 6 column-pairs, via THREE
// dword-aligned float4 loads (p-2, p+2, p+6); pair boundaries line up
// exactly, zero repack. Border threads patch the invalid half with f2. ----
__device__ __forceinline__ void ldw(v2 w[6], const float* __restrict__ p,
                                    bool rowok, bool lok, bool rok) {
    float4 q0 = make_float4(0.f, 0.f, 0.f, 0.f), q1 = q0, q2 = q0;
    if (rowok) {
        if (lok) {
            q0 = *(const float4*)(p - 2);          // cols gx-2 .. gx+1
        } else {
            float2 t = *(const float2*)p;          // cols gx, gx+1
            q0.z = t.x; q0.w = t.y;
        }
        q1 = *(const float4*)(p + 2);              // cols gx+2 .. gx+5
        if (rok) {
            q2 = *(const float4*)(p + 6);          // cols gx+6 .. gx+9
        } else {
            float2 t = *(const float2*)(p + 6);    // cols gx+6, gx+7
            q2.x = t.x; q2.y = t.y;
        }
    }
    w[0].x = q0.x; w[0].y = q0.y;  w[1].x = q0.z; w[1].y = q0.w;
    w[2].x = q1.x; w[2].y = q1.y;  w[3].x = q1.z; w[3].y = q1.w;
    w[4].x = q2.x; w[4].y = q2.y;  w[5].x = q2.z; w[5].y = q2.w;
}

// ---- packed squared-Sobel row: 3 raw windows (pairs, base gx-2) ->
// 5 pairs of squared magnitude on the odd-base grid (cols gx-1 .. gx+8).
// maxpool commutes with squaring, so no sqrt here. ----
__device__ __forceinline__ void e2pairs(const v2 a[6], const v2 b[6],
                                        const v2 c[6], v2 E[5]) {
    v2 t2[6], dz[6];
    #pragma unroll
    for (int k = 0; k < 6; ++k) {
        t2[k] = (a[k] + c[k]) + 2.0f * b[k];
        dz[k] = c[k] - a[k];
    }
    #pragma unroll
    for (int n = 0; n < 5; ++n) {
        v2 gxn = t2[n + 1] - t2[n];
        v2 sh;  sh.x = dz[n].y; sh.y = dz[n + 1].x;
        v2 gyn = (dz[n] + dz[n + 1]) + 2.0f * sh;
        E[n] = gxn * gxn + gyn * gyn;
    }
}

// ---- (pe-1)^2 for 8 output cols, packed to 4 half-pairs (16-bit storage
// safe: d^2 bounded, rel err ~1e-3 vs ~2% loss threshold; verified R8-R13). ----
__device__ __forceinline__ void mk_d2(const v2 S[5], h2 d2[4]) {
    float sp[10];
    #pragma unroll
    for (int n = 0; n < 5; ++n) {
        sp[2 * n]     = rsq(S[n].x);
        sp[2 * n + 1] = rsq(S[n].y);
    }   // sp[0], sp[9] dead -> DCE'd (8 live sqrt)
    #pragma unroll
    for (int n = 0; n < 4; ++n) {
        float dx = sp[2 * n + 1] - 1.f;
        float dy = sp[2 * n + 2] - 1.f;
        d2[n].x = (_Float16)(dx * dx);
        d2[n].y = (_Float16)(dy * dy);
    }
}

// ---- packed loss row: m[5] = pooled-e2 pairs on odd grid; output pair j
// (cols 2j,2j+1 of the 8) needs max of 3 adjacent odd-grid values. ----
__device__ __forceinline__ void loss_row(const v2 m[5], const h2 d2[4],
                                         v2& ls2) {
    #pragma unroll
    for (int j = 0; j < 4; ++j) {
        v2 mm = pmax2(m[j], m[j + 1]);
        v2 S;  S.x = m[j].y;  S.y = m[j + 1].x;
        v2 mp = pmax2(mm, S);                 // packed 3-wide horizontal max
        v2 q;  q.x = (float)d2[j].x;  q.y = (float)d2[j].y;
        ls2 = mp * q + ls2;                   // pk_fma
    }
}

#define SET1(M0)            { _Pragma("unroll") for (int n = 0; n < 5; ++n) M0[n] = E[n]; }
#define F1(M0)              { _Pragma("unroll") for (int n = 0; n < 5; ++n) M0[n] = pmax2(M0[n], E[n]); }
#define F1S1(M0, M1)        { _Pragma("unroll") for (int n = 0; n < 5; ++n) { M0[n] = pmax2(M0[n], E[n]); M1[n] = E[n]; } }
#define F2S1(M0, M1, M2)    { _Pragma("unroll") for (int n = 0; n < 5; ++n) { M0[n] = pmax2(M0[n], E[n]); M1[n] = pmax2(M1[n], E[n]); M2[n] = E[n]; } }
#define F2(M0, M1)          { _Pragma("unroll") for (int n = 0; n < 5; ++n) { M0[n] = pmax2(M0[n], E[n]); M1[n] = pmax2(M1[n], E[n]); } }
#define MASK(M)             { if (!lok) M[0].x = 0.f; if (!rok) M[4].y = 0.f; }

// One thread: 8 cols x 4 output rows (gy .. gy+3).
template<bool GR>
__device__ __forceinline__ float task4(const float* __restrict__ pIn,
                                       const float* __restrict__ pTg,
                                       int gy, int px) {
    const int gx = px << 3;
    const bool lok = (px > 0);
    const bool rok = (px < PXROW - 1);
    const float* tg = pTg + (size_t)gy * W + gx;
    const float* in = pIn + (size_t)gy * W + gx;
    v2 ls2 = (v2)(0.f);

    // ---- input phase: pe rows gy..gy+3 -> (pe-1)^2 packed halves ----
    h2 d20[4], d21[4], d22[4], d23[4];
    {
        v2 IA[6], IB[6], IC[6], S[5];
        ldw(IA, in - 1 * W, !GR || (gy >= 1), lok, rok);
        ldw(IB, in,          true,            lok, rok);
        ldw(IC, in + 1 * W,  true,            lok, rok);
        e2pairs(IA, IB, IC, S); mk_d2(S, d20);           // row gy
        ldw(IA, in + 2 * W, true, lok, rok);
        e2pairs(IB, IC, IA, S); mk_d2(S, d21);           // row gy+1
        ldw(IB, in + 3 * W, true, lok, rok);
        e2pairs(IC, IA, IB, S); mk_d2(S, d22);           // row gy+2
        ldw(IC, in + 4 * W, !GR || (gy + 4 < H), lok, rok);
        e2pairs(IA, IB, IC, S); mk_d2(S, d23);           // row gy+3
    }

    // ---- target phase: e2 rows gy-1..gy+4, immediate-consume m ----
    {
        v2 A[6], Bv[6], C[6], E[5];
        v2 m0[5], m1[5], m2[5], m3[5];
        ldw(A,  tg - 2 * W, !GR || (gy >= 2), lok, rok);
        ldw(Bv, tg - 1 * W, !GR || (gy >= 1), lok, rok);
        ldw(C,  tg,          true,            lok, rok);
        if (!GR || gy >= 1) {                  // e2 row gy-1
            e2pairs(A, Bv, C, E); SET1(m0);
        } else {
            #pragma unroll
            for (int n = 0; n < 5; ++n) m0[n] = (v2)(0.f);
        }
        ldw(A, tg + 1 * W, true, lok, rok);
        e2pairs(Bv, C, A, E); F1S1(m0, m1);    // e2 row gy
        ldw(Bv, tg + 2 * W, true, lok, rok);
        e2pairs(C, A, Bv, E); F2S1(m0, m1, m2);// e2 row gy+1; m0 complete
        MASK(m0); loss_row(m0, d20, ls2);
        ldw(C, tg + 3 * W, true, lok, rok);
        e2pairs(A, Bv, C, E); F2S1(m1, m2, m3);// e2 row gy+2; m1 complete
        MASK(m1); loss_row(m1, d21, ls2);
        ldw(A, tg + 4 * W, !GR || (gy + 4 < H), lok, rok);
        e2pairs(Bv, C, A, E); F2(m2, m3);      // e2 row gy+3; m2 complete
        MASK(m2); loss_row(m2, d22, ls2);
        if (!GR || (gy + 4 < H)) {             // e2 row gy+4 (skip if OOB)
            ldw(Bv, tg + 5 * W, !GR || (gy + 5 < H), lok, rok);
            e2pairs(C, A, Bv, E); F1(m3);
        }
        MASK(m3); loss_row(m3, d23, ls2);
    }
    return ls2.x + ls2.y;
}

__global__ __launch_bounds__(NT) void edge_loss_main(
    const float* __restrict__ inp, const float* __restrict__ tgt,
    double* __restrict__ part) {
    // XCD-bijective swizzle: hw-consecutive blocks on one XCD become
    // image-adjacent row-blocks (NBLK % NXCD == 0 -> bijective).
    const int bid = blockIdx.x;
    const int lb  = (bid & (NXCD - 1)) * (NBLK / NXCD) + (bid >> 3);
    const int b      = lb >> 7;            // / NRB (128)
    const int rowblk = lb & (NRB - 1);

    const float* pIn = inp + (size_t)b * (H * W);
    const float* pTg = tgt + (size_t)b * (H * W);
    const int tid  = threadIdx.x;
    const int px   = tid & (PXROW - 1);
    const int band = tid >> 7;
    const int gy   = rowblk * RPB + band * 4;

    const bool gr = (rowblk == 0) | (rowblk == NRB - 1);
    float ls = gr ? task4<true >(pIn, pTg, gy, px)
                  : task4<false>(pIn, pTg, gy, px);

    // ---- reduce: wave64 shuffle -> LDS -> one plain store per block ----
    #pragma unroll
    for (int off = 32; off > 0; off >>= 1)
        ls += __shfl_down(ls, off);
    __shared__ float wsum[NT / 64];
    const int wave = tid >> 6, lane = tid & 63;
    if (lane == 0) wsum[wave] = ls;
    __syncthreads();
    if (tid == 0) {
        float bsum = 0.f;
        #pragma unroll
        for (int w2 = 0; w2 < NT / 64; ++w2) bsum += wsum[w2];
        part[bid] = (double)bsum;   // deterministic overwrite; no init needed
    }
}

__global__ __launch_bounds__(NT) void edge_loss_finalize(
    const double* __restrict__ part, float* __restrict__ out) {
    const int tid = threadIdx.x;
    double s = 0.0;
    #pragma unroll
    for (int k = 0; k < NBLK / NT; ++k)      // 8 strided loads each
        s += part[tid + k * NT];
    #pragma unroll
    for (int off = 32; off > 0; off >>= 1)
        s += __shfl_down(s, off);
    __shared__ double wsum[NT / 64];
    const int wave = tid >> 6, lane = tid & 63;
    if (lane == 0) wsum[wave] = s;
    __syncthreads();
    if (tid == 0) {
        double t = 0.0;
        #pragma unroll
        for (int w2 = 0; w2 < NT / 64; ++w2) t += wsum[w2];
        out[0] = (float)(t / (double)((size_t)BATCH * H * W));
    }
}

extern "C" void kernel_launch(void* const* d_in, const int* in_sizes, int n_in,
                              void* d_out, int out_size, void* d_ws, size_t ws_size,
                              hipStream_t stream) {
    const float* inputs  = (const float*)d_in[0];
    const float* targets = (const float*)d_in[1];
    float* out   = (float*)d_out;
    double* part = (double*)d_ws;            // NBLK doubles = 16 KB scratch

    edge_loss_main<<<dim3(NBLK), NT, 0, stream>>>(inputs, targets, part);
    edge_loss_finalize<<<1, NT, 0, stream>>>(part, out);
}

// Round 15
// 33.936 us; speedup vs baseline: 1.4760x; 1.4760x over previous
//
#include <hip/hip_runtime.h>

#define H 1024
#define W 1024
#define BATCH 16
#define NT 256
#define PXROW 128            // threads across one row-band (8 px each)
#define RPB 8                // image rows per block (2 bands x 4 rows)
#define NRB (H / RPB)        // 128 row-blocks per image
#define NBLK (NRB * BATCH)   // 2048 blocks
#define NXCD 8

typedef float v2 __attribute__((ext_vector_type(2)));

__device__ __forceinline__ v2 pmax2(v2 a, v2 b) {
#if __has_builtin(__builtin_elementwise_max)
    return __builtin_elementwise_max(a, b);
#else
    v2 r; r.x = fmaxf(a.x, b.x); r.y = fmaxf(a.y, b.y); return r;
#endif
}

// raw v_sqrt_f32 (~1 ulp) — avoids OCML correctly-rounded fixup sequence
__device__ __forceinline__ float rsq(float x) {
#if __has_builtin(__builtin_amdgcn_sqrtf)
    return __builtin_amdgcn_sqrtf(x);
#else
    return sqrtf(x);
#endif
}

// ---- 12-col window (cols gx-2 .. gx+9) as 6 column-pairs; pairs aligned:
// f2@gx-2, f4@gx, f4@gx+4, f2@gx+8 (all naturally aligned — R14 showed
// misaligned f4 line-crossing costs 1.5x; keep this decomposition). ----
__device__ __forceinline__ void ldw(v2 w[6], const float* __restrict__ p,
                                    bool rowok, bool lok, bool rok) {
    float2 a = make_float2(0.f, 0.f), d = make_float2(0.f, 0.f);
    float4 b = make_float4(0.f, 0.f, 0.f, 0.f), c = b;
    if (rowok) {
        if (lok) a = *(const float2*)(p - 2);
        b = *(const float4*)p;
        c = *(const float4*)(p + 4);
        if (rok) d = *(const float2*)(p + 8);
    }
    w[0].x = a.x; w[0].y = a.y;
    w[1].x = b.x; w[1].y = b.y;  w[2].x = b.z; w[2].y = b.w;
    w[3].x = c.x; w[3].y = c.y;  w[4].x = c.z; w[4].y = c.w;
    w[5].x = d.x; w[5].y = d.y;
}

// ---- packed squared-Sobel row: 3 raw windows (pairs, base gx-2) ->
// 5 pairs of squared magnitude on the odd-base grid (cols gx-1 .. gx+8).
// maxpool commutes with squaring, so no sqrt here. ----
__device__ __forceinline__ void e2pairs(const v2 a[6], const v2 b[6],
                                        const v2 c[6], v2 E[5]) {
    v2 t2[6], dz[6];
    #pragma unroll
    for (int k = 0; k < 6; ++k) {
        t2[k] = (a[k] + c[k]) + 2.0f * b[k];
        dz[k] = c[k] - a[k];
    }
    #pragma unroll
    for (int n = 0; n < 5; ++n) {
        v2 gxn = t2[n + 1] - t2[n];
        v2 sh;  sh.x = dz[n].y; sh.y = dz[n + 1].x;
        v2 gyn = (dz[n] + dz[n + 1]) + 2.0f * sh;
        E[n] = gxn * gxn + gyn * gyn;
    }
}

// ---- (pe-1)^2 for 8 output cols as 4 f32 pairs (no half round-trip) ----
__device__ __forceinline__ void mk_d2(const v2 S[5], v2 d2[4]) {
    float sp[10];
    #pragma unroll
    for (int n = 0; n < 5; ++n) {
        sp[2 * n]     = rsq(S[n].x);
        sp[2 * n + 1] = rsq(S[n].y);
    }   // sp[0], sp[9] dead -> DCE'd (8 live sqrt)
    #pragma unroll
    for (int n = 0; n < 4; ++n) {
        float dx = sp[2 * n + 1] - 1.f;
        float dy = sp[2 * n + 2] - 1.f;
        d2[n].x = dx * dx;
        d2[n].y = dy * dy;
    }
}

// ---- packed loss row: m[5] = pooled-e2 pairs on odd grid; output pair j
// (cols 2j,2j+1 of the 8) needs max of 3 adjacent odd-grid values. ----
__device__ __forceinline__ void loss_row(const v2 m[5], const v2 d2[4],
                                         v2& ls2) {
    #pragma unroll
    for (int j = 0; j < 4; ++j) {
        v2 mm = pmax2(m[j], m[j + 1]);
        v2 S;  S.x = m[j].y;  S.y = m[j + 1].x;
        v2 mp = pmax2(mm, S);                 // packed 3-wide horizontal max
        ls2 = mp * d2[j] + ls2;               // pk_fma
    }
}

#define SET1(M0)            { _Pragma("unroll") for (int n = 0; n < 5; ++n) M0[n] = E[n]; }
#define F1(M0)              { _Pragma("unroll") for (int n = 0; n < 5; ++n) M0[n] = pmax2(M0[n], E[n]); }
#define F1S1(M0, M1)        { _Pragma("unroll") for (int n = 0; n < 5; ++n) { M0[n] = pmax2(M0[n], E[n]); M1[n] = E[n]; } }
#define F2S1(M0, M1, M2)    { _Pragma("unroll") for (int n = 0; n < 5; ++n) { M0[n] = pmax2(M0[n], E[n]); M1[n] = pmax2(M1[n], E[n]); M2[n] = E[n]; } }
#define F2(M0, M1)          { _Pragma("unroll") for (int n = 0; n < 5; ++n) { M0[n] = pmax2(M0[n], E[n]); M1[n] = pmax2(M1[n], E[n]); } }
#define MASK(M)             { if (!lok) M[0].x = 0.f; if (!rok) M[4].y = 0.f; }

// One thread: 8 cols x 4 output rows (gy .. gy+3).
template<bool GR>
__device__ __forceinline__ float task4(const float* __restrict__ pIn,
                                       const float* __restrict__ pTg,
                                       int gy, int px) {
    const int gx = px << 3;
    const bool lok = (px > 0);
    const bool rok = (px < PXROW - 1);
    const float* tg = pTg + (size_t)gy * W + gx;
    const float* in = pIn + (size_t)gy * W + gx;
    v2 ls2 = (v2)(0.f);

    // ---- input phase: pe rows gy..gy+3 -> (pe-1)^2 f32 pairs ----
    v2 d20[4], d21[4], d22[4], d23[4];
    {
        v2 IA[6], IB[6], IC[6], S[5];
        ldw(IA, in - 1 * W, !GR || (gy >= 1), lok, rok);
        ldw(IB, in,          true,            lok, rok);
        ldw(IC, in + 1 * W,  true,            lok, rok);
        e2pairs(IA, IB, IC, S); mk_d2(S, d20);           // row gy
        ldw(IA, in + 2 * W, true, lok, rok);
        e2pairs(IB, IC, IA, S); mk_d2(S, d21);           // row gy+1
        ldw(IB, in + 3 * W, true, lok, rok);
        e2pairs(IC, IA, IB, S); mk_d2(S, d22);           // row gy+2
        ldw(IC, in + 4 * W, !GR || (gy + 4 < H), lok, rok);
        e2pairs(IA, IB, IC, S); mk_d2(S, d23);           // row gy+3
    }

    // ---- target phase: e2 rows gy-1..gy+4, immediate-consume m ----
    {
        v2 A[6], Bv[6], C[6], E[5];
        v2 m0[5], m1[5], m2[5], m3[5];
        ldw(A,  tg - 2 * W, !GR || (gy >= 2), lok, rok);
        ldw(Bv, tg - 1 * W, !GR || (gy >= 1), lok, rok);
        ldw(C,  tg,          true,            lok, rok);
        if (!GR || gy >= 1) {                  // e2 row gy-1
            e2pairs(A, Bv, C, E); SET1(m0);
        } else {
            #pragma unroll
            for (int n = 0; n < 5; ++n) m0[n] = (v2)(0.f);
        }
        ldw(A, tg + 1 * W, true, lok, rok);
        e2pairs(Bv, C, A, E); F1S1(m0, m1);    // e2 row gy
        ldw(Bv, tg + 2 * W, true, lok, rok);
        e2pairs(C, A, Bv, E); F2S1(m0, m1, m2);// e2 row gy+1; m0 complete
        MASK(m0); loss_row(m0, d20, ls2);
        ldw(C, tg + 3 * W, true, lok, rok);
        e2pairs(A, Bv, C, E); F2S1(m1, m2, m3);// e2 row gy+2; m1 complete
        MASK(m1); loss_row(m1, d21, ls2);
        ldw(A, tg + 4 * W, !GR || (gy + 4 < H), lok, rok);
        e2pairs(Bv, C, A, E); F2(m2, m3);      // e2 row gy+3; m2 complete
        MASK(m2); loss_row(m2, d22, ls2);
        if (!GR || (gy + 4 < H)) {             // e2 row gy+4 (skip if OOB)
            ldw(Bv, tg + 5 * W, !GR || (gy + 5 < H), lok, rok);
            e2pairs(C, A, Bv, E); F1(m3);
        }
        MASK(m3); loss_row(m3, d23, ls2);
    }
    return ls2.x + ls2.y;
}

__global__ __launch_bounds__(NT) void edge_loss_main(
    const float* __restrict__ inp, const float* __restrict__ tgt,
    double* __restrict__ part) {
    // XCD-bijective swizzle: hw-consecutive blocks on one XCD become
    // image-adjacent row-blocks (NBLK % NXCD == 0 -> bijective).
    const int bid = blockIdx.x;
    const int lb  = (bid & (NXCD - 1)) * (NBLK / NXCD) + (bid >> 3);
    const int b      = lb >> 7;            // / NRB (128)
    const int rowblk = lb & (NRB - 1);

    const float* pIn = inp + (size_t)b * (H * W);
    const float* pTg = tgt + (size_t)b * (H * W);
    const int tid  = threadIdx.x;
    const int px   = tid & (PXROW - 1);
    const int band = tid >> 7;
    const int gy   = rowblk * RPB + band * 4;

    const bool gr = (rowblk == 0) | (rowblk == NRB - 1);
    float ls = gr ? task4<true >(pIn, pTg, gy, px)
                  : task4<false>(pIn, pTg, gy, px);

    // ---- reduce: wave64 shuffle -> LDS -> one plain store per block ----
    #pragma unroll
    for (int off = 32; off > 0; off >>= 1)
        ls += __shfl_down(ls, off);
    __shared__ float wsum[NT / 64];
    const int wave = tid >> 6, lane = tid & 63;
    if (lane == 0) wsum[wave] = ls;
    __syncthreads();
    if (tid == 0) {
        float bsum = 0.f;
        #pragma unroll
        for (int w2 = 0; w2 < NT / 64; ++w2) bsum += wsum[w2];
        part[bid] = (double)bsum;   // deterministic overwrite; no init needed
    }
}

__global__ __launch_bounds__(NT) void edge_loss_finalize(
    const double* __restrict__ part, float* __restrict__ out) {
    const int tid = threadIdx.x;
    double s = 0.0;
    #pragma unroll
    for (int k = 0; k < NBLK / NT; ++k)      // 8 strided loads each
        s += part[tid + k * NT];
    #pragma unroll
    for (int off = 32; off > 0; off >>= 1)
        s += __shfl_down(s, off);
    __shared__ double wsum[NT / 64];
    const int wave = tid >> 6, lane = tid & 63;
    if (lane == 0) wsum[wave] = s;
    __syncthreads();
    if (tid == 0) {
        double t = 0.0;
        #pragma unroll
        for (int w2 = 0; w2 < NT / 64; ++w2) t += wsum[w2];
        out[0] = (float)(t / (double)((size_t)BATCH * H * W));
    }
}

extern "C" void kernel_launch(void* const* d_in, const int* in_sizes, int n_in,
                              void* d_out, int out_size, void* d_ws, size_t ws_size,
                              hipStream_t stream) {
    const float* inputs  = (const float*)d_in[0];
    const float* targets = (const float*)d_in[1];
    float* out   = (float*)d_out;
    double* part = (double*)d_ws;            // NBLK doubles = 16 KB scratch

    edge_loss_main<<<dim3(NBLK), NT, 0, stream>>>(inputs, targets, part);
    edge_loss_finalize<<<1, NT, 0, stream>>>(part, out);
}